// Round 20
// baseline (124.159 us; speedup 1.0000x reference)
//
#include <hip/hip_runtime.h>

// CenterShift: out[n,o] = x[n] * (celu(celu((pos_j-pos_i)@w11+b11)@w12+b12) @ w13 + b13)[o]
// N = 2097152, dims 3 -> 16 -> 64 -> 64, fp32 in/out.
//
// Round 20 = r19 (121.5us best) with ONE change: the deferred drain pipeline
// is made CONTINUOUS across t2 groups AND tile iterations. r19 still paid a
// serial tail drain (lgkm + 16 stores) per tile; now the pending group is
// carried as a wave-uniform pointer (og_pend -> SGPR, zero VGPR cost) and
// drained after the NEXT group's MFMAs -- across the tile boundary, group 3
// of tile t drains under layer-1/2 + MFMA(group 0) of tile t+1.
// WAR safety unchanged (program-order DS): pending reads issue before the
// overwriting bounce-writes; h2s/stg are disjoint so layer-2 doesn't touch
// the bounce. N = 2048 blocks x 1024 pts exactly -> no tail hazards.
// Settled invariants: f32 bounce + contiguous 1KB-per-instr NT stores;
// scalar layer-2; swizzled h2 tile; 4-tile loop + pos prefetch; 2048 blocks;
// no extra persistent VGPRs; per-wave LDS; no __syncthreads.

typedef __attribute__((ext_vector_type(8))) _Float16 f16x8;
typedef __attribute__((ext_vector_type(4))) float f32x4;

#define TILES 4

__device__ __forceinline__ float celu1(float a) {
    return a > 0.0f ? a : __expf(a) - 1.0f;
}

__device__ __forceinline__ void drain_group(const char* stgb, float* og, int lane) {
#pragma unroll
    for (int k = 0; k < 4; ++k) {
        const int ptl = k * 4 + (lane >> 4);   // local point 0..15
        const int c   = lane & 15;             // 16B channel block
        const int rb  = ptl * 256 + ((c * 16) ^ ((ptl & 7) << 4));
        const f32x4 v = *reinterpret_cast<const f32x4*>(stgb + rb);
        __builtin_nontemporal_store(v, reinterpret_cast<f32x4*>(og + k * 256 + lane * 4));
    }
}

__global__ __launch_bounds__(256) void centershift_kernel(
    const float* __restrict__ x,
    const float* __restrict__ pos_i,
    const float* __restrict__ pos_j,
    const float* __restrict__ w11, const float* __restrict__ b11,
    const float* __restrict__ w12, const float* __restrict__ b12,
    const float* __restrict__ w13, const float* __restrict__ b13,
    float* __restrict__ out, int n)
{
    __shared__ __align__(16) _Float16 h2s[4][64 * 64];  // 8 KB/wave, swizzled
    __shared__ __align__(16) float    stg[4][1024];     // 4 KB/wave bounce

    const int lane = threadIdx.x & 63;
    const int wid  = threadIdx.x >> 6;
    const int g    = lane >> 4;    // 16-lane group 0..3
    const int r16  = lane & 15;

    const int wbase = (blockIdx.x * 4 + wid) * (64 * TILES);
    if (wbase >= n) return;

    char* h2b  = (char*)&h2s[wid][0];
    char* stgb = (char*)&stg[wid][0];

    // ---- hoisted fragments (issue first; overlap tile-0 compute) ----
    // layer-3 A = w13^T: A[row = u*16 + r16][k = kh*32 + g*8 + j]
    f16x8 a3[4][2];
#pragma unroll
    for (int u = 0; u < 4; ++u)
#pragma unroll
        for (int kh = 0; kh < 2; ++kh) {
            f16x8 v;
#pragma unroll
            for (int j = 0; j < 8; ++j)
                v[j] = (_Float16)w13[(kh * 32 + g * 8 + j) * 64 + u * 16 + r16];
            a3[u][kh] = v;
        }
    // bias in C/D layout: lane holds o = u*16 + g*4 + rr
    float b3v[4][4];
#pragma unroll
    for (int u = 0; u < 4; ++u) {
        const float4 bv = *reinterpret_cast<const float4*>(b13 + u * 16 + g * 4);
        b3v[u][0] = bv.x; b3v[u][1] = bv.y; b3v[u][2] = bv.z; b3v[u][3] = bv.w;
    }

    // ---- preload tile-0 pos (lane = its own point) ----
    const float* pip = pos_i + 3 * (size_t)(wbase + lane);
    const float* pjp = pos_j + 3 * (size_t)(wbase + lane);
    float3 cpi = *reinterpret_cast<const float3*>(pip);
    float3 cpj = *reinterpret_cast<const float3*>(pjp);

    const int swzW = (lane & 7) << 4;
    const int rowW = lane * 128;
    const int swzR = (r16 & 7) << 4;

    float* og_pend = nullptr;   // wave-uniform pending-drain pointer (SGPR)

#pragma unroll 1
    for (int t = 0; t < TILES; ++t) {
        const int tb = wbase + t * 64;
        if (tb >= n) break;

        const float p0 = cpj.x - cpi.x, p1 = cpj.y - cpi.y, p2 = cpj.z - cpi.z;

        // ---- layer 1: 3 -> 16 ----
        float h1[16];
#pragma unroll
        for (int j = 0; j < 16; ++j) {
            float a = b11[j];
            a = fmaf(p0, w11[j], a);
            a = fmaf(p1, w11[16 + j], a);
            a = fmaf(p2, w11[32 + j], a);
            h1[j] = celu1(a);
        }

        // prefetch next tile's pos (hidden under the compute below)
        if (t + 1 < TILES) {
            cpi = *reinterpret_cast<const float3*>(pip + (t + 1) * 192);
            cpj = *reinterpret_cast<const float3*>(pjp + (t + 1) * 192);
        }

        // ---- layer 2: 16 -> 64 scalar (wave-uniform weights), to swizzled LDS ----
        for (int c = 0; c < 8; ++c) {
            f16x8 v;
#pragma unroll
            for (int j = 0; j < 8; ++j) {
                const int o = c * 8 + j;
                float a = b12[o];
#pragma unroll
                for (int k = 0; k < 16; ++k)
                    a = fmaf(h1[k], w12[k * 64 + o], a);
                v[j] = (_Float16)celu1(a);
            }
            *reinterpret_cast<f16x8*>(h2b + (rowW + ((c * 16) ^ swzW))) = v;
        }

        // ---- layer 3: MFMA(t2) ; drain(pending) ; bounce-write(t2) ----
#pragma unroll
        for (int t2 = 0; t2 < 4; ++t2) {
            const int pt   = t2 * 16 + r16;
            const int rowR = pt * 128;
            const f16x8 bb0 = *reinterpret_cast<const f16x8*>(h2b + (rowR + ((     g * 16) ^ swzR)));
            const f16x8 bb1 = *reinterpret_cast<const f16x8*>(h2b + (rowR + ((64 + g * 16) ^ swzR)));
            const float xvt = x[tb + pt];          // 1 line, L1 broadcast
            f32x4 o4s[4];
#pragma unroll
            for (int u = 0; u < 4; ++u) {
                f32x4 acc = { b3v[u][0], b3v[u][1], b3v[u][2], b3v[u][3] };
                acc = __builtin_amdgcn_mfma_f32_16x16x32_f16(a3[u][0], bb0, acc, 0, 0, 0);
                acc = __builtin_amdgcn_mfma_f32_16x16x32_f16(a3[u][1], bb1, acc, 0, 0, 0);
                o4s[u][0] = acc[0] * xvt; o4s[u][1] = acc[1] * xvt;
                o4s[u][2] = acc[2] * xvt; o4s[u][3] = acc[3] * xvt;
            }
            // drain pending group (reads issued before this group's writes;
            // in-order DS pipe -> returns old data; latency hid under MFMAs
            // and, across tiles, under layer-1/2 as well)
            if (og_pend) drain_group(stgb, og_pend, lane);
            // bounce-write this group (overwrites only after the drain reads)
#pragma unroll
            for (int u = 0; u < 4; ++u) {
                const int wb = r16 * 256 + (((u * 64 + g * 16)) ^ ((r16 & 7) << 4));
                *reinterpret_cast<f32x4*>(stgb + wb) = o4s[u];
            }
            og_pend = out + (size_t)(tb + t2 * 16) * 64;
        }
    }
    // final pending drain
    if (og_pend) drain_group(stgb, og_pend, lane);
}

extern "C" void kernel_launch(void* const* d_in, const int* in_sizes, int n_in,
                              void* d_out, int out_size, void* d_ws, size_t ws_size,
                              hipStream_t stream) {
    const float* x     = (const float*)d_in[0];
    const float* pos_i = (const float*)d_in[1];
    const float* pos_j = (const float*)d_in[2];
    const float* w11   = (const float*)d_in[3];
    const float* b11   = (const float*)d_in[4];
    const float* w12   = (const float*)d_in[5];
    const float* b12   = (const float*)d_in[6];
    const float* w13   = (const float*)d_in[7];
    const float* b13   = (const float*)d_in[8];
    float* out = (float*)d_out;

    const int n = in_sizes[0];                        // N (x is [N,1])
    const int per_block = 256 * TILES;                // 4 waves x 4 tiles x 64 pts
    const int blocks = (n + per_block - 1) / per_block;
    centershift_kernel<<<blocks, 256, 0, stream>>>(
        x, pos_i, pos_j, w11, b11, w12, b12, w13, b13, out, n);
}

// Round 21
// 123.090 us; speedup vs baseline: 1.0087x; 1.0087x over previous
//
#include <hip/hip_runtime.h>

// CenterShift: out[n,o] = x[n] * (celu(celu((pos_j-pos_i)@w11+b11)@w12+b12) @ w13 + b13)[o]
// N = 2097152, dims 3 -> 16 -> 64 -> 64, fp32 in/out.
//
// Round 21 = r19 (121.5us best; r20's cross-tile pipeline reverted) with ONE
// change: s_setprio(1) around each drain. Waves here are barrier-free and
// independent (the regime where setprio measured +4-7%; null only in
// barrier-lockstep kernels). Theory: at 3 waves/SIMD the store pipe idles
// when co-resident waves align in compute phases; prioritizing a wave during
// its drain wins issue-arbitration slots for the 16 nt stores, raising store
// duty cycle. Zero structural change, zero VGPR/LDS delta.
// Settled invariants: f32 bounce + contiguous 1KB-per-instr NT stores
// (r9/r15/r16/r17); drain deferred by exactly ONE group (r19 win, r20's
// deeper pipeline regressed); scalar layer-2 (MFMA-l2 lost 4x); swizzled h2
// tile; 4-tile loop + pos prefetch; 2048 blocks (r18); no extra persistent
// VGPRs (r11); per-wave LDS; no __syncthreads.

typedef __attribute__((ext_vector_type(8))) _Float16 f16x8;
typedef __attribute__((ext_vector_type(4))) float f32x4;

#define TILES 4

__device__ __forceinline__ float celu1(float a) {
    return a > 0.0f ? a : __expf(a) - 1.0f;
}

__global__ __launch_bounds__(256) void centershift_kernel(
    const float* __restrict__ x,
    const float* __restrict__ pos_i,
    const float* __restrict__ pos_j,
    const float* __restrict__ w11, const float* __restrict__ b11,
    const float* __restrict__ w12, const float* __restrict__ b12,
    const float* __restrict__ w13, const float* __restrict__ b13,
    float* __restrict__ out, int n)
{
    __shared__ __align__(16) _Float16 h2s[4][64 * 64];  // 8 KB/wave, swizzled
    __shared__ __align__(16) float    stg[4][1024];     // 4 KB/wave bounce

    const int lane = threadIdx.x & 63;
    const int wid  = threadIdx.x >> 6;
    const int g    = lane >> 4;    // 16-lane group 0..3
    const int r16  = lane & 15;

    const int wbase = (blockIdx.x * 4 + wid) * (64 * TILES);
    if (wbase >= n) return;

    char* h2b  = (char*)&h2s[wid][0];
    char* stgb = (char*)&stg[wid][0];

    // ---- hoisted fragments (issue first; overlap tile-0 compute) ----
    // layer-3 A = w13^T: A[row = u*16 + r16][k = kh*32 + g*8 + j]
    f16x8 a3[4][2];
#pragma unroll
    for (int u = 0; u < 4; ++u)
#pragma unroll
        for (int kh = 0; kh < 2; ++kh) {
            f16x8 v;
#pragma unroll
            for (int j = 0; j < 8; ++j)
                v[j] = (_Float16)w13[(kh * 32 + g * 8 + j) * 64 + u * 16 + r16];
            a3[u][kh] = v;
        }
    // bias in C/D layout: lane holds o = u*16 + g*4 + rr
    float b3v[4][4];
#pragma unroll
    for (int u = 0; u < 4; ++u) {
        const float4 bv = *reinterpret_cast<const float4*>(b13 + u * 16 + g * 4);
        b3v[u][0] = bv.x; b3v[u][1] = bv.y; b3v[u][2] = bv.z; b3v[u][3] = bv.w;
    }

    // ---- preload tile-0 pos (lane = its own point) ----
    const float* pip = pos_i + 3 * (size_t)(wbase + lane);
    const float* pjp = pos_j + 3 * (size_t)(wbase + lane);
    float3 cpi = *reinterpret_cast<const float3*>(pip);
    float3 cpj = *reinterpret_cast<const float3*>(pjp);

    const int swzW = (lane & 7) << 4;
    const int rowW = lane * 128;
    const int swzR = (r16 & 7) << 4;

#pragma unroll 1
    for (int t = 0; t < TILES; ++t) {
        const int tb = wbase + t * 64;
        if (tb >= n) break;

        const float p0 = cpj.x - cpi.x, p1 = cpj.y - cpi.y, p2 = cpj.z - cpi.z;

        // ---- layer 1: 3 -> 16 ----
        float h1[16];
#pragma unroll
        for (int j = 0; j < 16; ++j) {
            float a = b11[j];
            a = fmaf(p0, w11[j], a);
            a = fmaf(p1, w11[16 + j], a);
            a = fmaf(p2, w11[32 + j], a);
            h1[j] = celu1(a);
        }

        // prefetch next tile's pos (hidden under the compute below)
        if (t + 1 < TILES) {
            cpi = *reinterpret_cast<const float3*>(pip + (t + 1) * 192);
            cpj = *reinterpret_cast<const float3*>(pjp + (t + 1) * 192);
        }

        // ---- layer 2: 16 -> 64 scalar (wave-uniform weights), to swizzled LDS ----
        for (int c = 0; c < 8; ++c) {
            f16x8 v;
#pragma unroll
            for (int j = 0; j < 8; ++j) {
                const int o = c * 8 + j;
                float a = b12[o];
#pragma unroll
                for (int k = 0; k < 16; ++k)
                    a = fmaf(h1[k], w12[k * 64 + o], a);
                v[j] = (_Float16)celu1(a);
            }
            *reinterpret_cast<f16x8*>(h2b + (rowW + ((c * 16) ^ swzW))) = v;
        }

        // ---- layer 3: MFMA(t2) ; drain(t2-1) [prio 1] ; bounce-write(t2) ----
#pragma unroll
        for (int t2 = 0; t2 < 4; ++t2) {
            const int pt   = t2 * 16 + r16;
            const int rowR = pt * 128;
            const f16x8 bb0 = *reinterpret_cast<const f16x8*>(h2b + (rowR + ((     g * 16) ^ swzR)));
            const f16x8 bb1 = *reinterpret_cast<const f16x8*>(h2b + (rowR + ((64 + g * 16) ^ swzR)));
            const float xvt = x[tb + pt];          // 1 line, L1 broadcast
            f32x4 o4s[4];
#pragma unroll
            for (int u = 0; u < 4; ++u) {
                f32x4 acc = { b3v[u][0], b3v[u][1], b3v[u][2], b3v[u][3] };
                acc = __builtin_amdgcn_mfma_f32_16x16x32_f16(a3[u][0], bb0, acc, 0, 0, 0);
                acc = __builtin_amdgcn_mfma_f32_16x16x32_f16(a3[u][1], bb1, acc, 0, 0, 0);
                o4s[u][0] = acc[0] * xvt; o4s[u][1] = acc[1] * xvt;
                o4s[u][2] = acc[2] * xvt; o4s[u][3] = acc[3] * xvt;
            }
            // drain PREVIOUS group under this group's MFMAs, at raised priority
            if (t2 > 0) {
                __builtin_amdgcn_s_setprio(1);
                float* og = out + (size_t)(tb + (t2 - 1) * 16) * 64;
#pragma unroll
                for (int k = 0; k < 4; ++k) {
                    const int ptl = k * 4 + (lane >> 4);   // local point 0..15
                    const int c   = lane & 15;             // 16B channel block
                    const int rb  = ptl * 256 + ((c * 16) ^ ((ptl & 7) << 4));
                    const f32x4 v = *reinterpret_cast<const f32x4*>(stgb + rb);
                    __builtin_nontemporal_store(v, reinterpret_cast<f32x4*>(og + k * 256 + lane * 4));
                }
                __builtin_amdgcn_s_setprio(0);
            }
            // bounce-write this group (overwrites only after the drain reads)
#pragma unroll
            for (int u = 0; u < 4; ++u) {
                const int wb = r16 * 256 + (((u * 64 + g * 16)) ^ ((r16 & 7) << 4));
                *reinterpret_cast<f32x4*>(stgb + wb) = o4s[u];
            }
        }
        {   // tail drain: group 3, at raised priority
            __builtin_amdgcn_s_setprio(1);
            float* og = out + (size_t)(tb + 3 * 16) * 64;
#pragma unroll
            for (int k = 0; k < 4; ++k) {
                const int ptl = k * 4 + (lane >> 4);
                const int c   = lane & 15;
                const int rb  = ptl * 256 + ((c * 16) ^ ((ptl & 7) << 4));
                const f32x4 v = *reinterpret_cast<const f32x4*>(stgb + rb);
                __builtin_nontemporal_store(v, reinterpret_cast<f32x4*>(og + k * 256 + lane * 4));
            }
            __builtin_amdgcn_s_setprio(0);
        }
    }
}

extern "C" void kernel_launch(void* const* d_in, const int* in_sizes, int n_in,
                              void* d_out, int out_size, void* d_ws, size_t ws_size,
                              hipStream_t stream) {
    const float* x     = (const float*)d_in[0];
    const float* pos_i = (const float*)d_in[1];
    const float* pos_j = (const float*)d_in[2];
    const float* w11   = (const float*)d_in[3];
    const float* b11   = (const float*)d_in[4];
    const float* w12   = (const float*)d_in[5];
    const float* b12   = (const float*)d_in[6];
    const float* w13   = (const float*)d_in[7];
    const float* b13   = (const float*)d_in[8];
    float* out = (float*)d_out;

    const int n = in_sizes[0];                        // N (x is [N,1])
    const int per_block = 256 * TILES;                // 4 waves x 4 tiles x 64 pts
    const int blocks = (n + per_block - 1) / per_block;
    centershift_kernel<<<blocks, 256, 0, stream>>>(
        x, pos_i, pos_j, w11, b11, w12, b12, w13, b13, out, n);
}